// Round 1
// baseline (642.348 us; speedup 1.0000x reference)
//
#include <hip/hip_runtime.h>
#include <stdint.h>

// ---------------- problem constants ----------------
#define T_TOK   2048          // B*S tokens
#define DMODEL  1024
#define DFF     4096
#define NEXP    8

// ---------------- workspace layout (bytes) ----------------
#define WS_CNT   0            // int[8]   per-expert token count
#define WS_BASE  1024         // int[8]   exclusive scan of counts
#define WS_TOKE  4096         // int[2*T] expert id per (token,k)
#define WS_TOKP  20480        // int[2*T] position within expert list
#define WS_TOKW  36864        // float[2*T] combine weight
#define WS_XG    65536        // f16[4096][1024] gathered tokens  (8 MB)
#define WS_H     16777216     // f16[4096][4096] swiglu output    (32 MB)
#define WS_Y     50331648     // f32[4096][1024] expert outputs   (16 MB)
// total 64 MB

typedef unsigned int  uint;
typedef unsigned short u16;
typedef _Float16 half8 __attribute__((ext_vector_type(8)));
typedef float    f32x4 __attribute__((ext_vector_type(4)));

__device__ __forceinline__ u16 f2h(float f) {
    union { _Float16 h; u16 u; } c;
    c.h = (_Float16)f;
    return c.u;
}

__device__ __forceinline__ uint4 pack8h(float4 a, float4 b) {
    uint4 r;
    r.x = (uint)f2h(a.x) | ((uint)f2h(a.y) << 16);
    r.y = (uint)f2h(a.z) | ((uint)f2h(a.w) << 16);
    r.z = (uint)f2h(b.x) | ((uint)f2h(b.y) << 16);
    r.w = (uint)f2h(b.z) | ((uint)f2h(b.w) << 16);
    return r;
}

// ---------------- 1. router: logits, top-2, softmax, slot grab ----------------
__global__ __launch_bounds__(256) void k_router(const float* __restrict__ x,
                                                const float* __restrict__ wr,
                                                char* __restrict__ ws) {
    int wid  = threadIdx.x >> 6;
    int lane = threadIdx.x & 63;
    int t = blockIdx.x * 4 + wid;   // 512 blocks * 4 waves = 2048 tokens

    float acc[NEXP];
#pragma unroll
    for (int e = 0; e < NEXP; ++e) acc[e] = 0.f;

    for (int i = 0; i < DMODEL / 64; ++i) {
        float xv = x[(size_t)t * DMODEL + i * 64 + lane];
#pragma unroll
        for (int e = 0; e < NEXP; ++e)
            acc[e] += xv * wr[e * DMODEL + i * 64 + lane];
    }
#pragma unroll
    for (int e = 0; e < NEXP; ++e) {
#pragma unroll
        for (int m = 32; m; m >>= 1) acc[e] += __shfl_xor(acc[e], m, 64);
    }
    if (lane == 0) {
        float l0 = -3.4e38f, l1 = -3.4e38f;
        int   e0 = 0, e1 = 0;
#pragma unroll
        for (int e = 0; e < NEXP; ++e) {
            float v = acc[e];
            if (v > l0)      { l1 = l0; e1 = e0; l0 = v; e0 = e; }
            else if (v > l1) { l1 = v;  e1 = e; }
        }
        float ew = expf(l1 - l0);            // softmax over the top-2 (desc order)
        float inv = 1.f / (1.f + ew);
        float w0 = inv, w1 = ew * inv;

        int* cnt = (int*)(ws + WS_CNT);
        int p0 = atomicAdd(&cnt[e0], 1);
        int p1 = atomicAdd(&cnt[e1], 1);
        int*   te = (int*)(ws + WS_TOKE);
        int*   tp = (int*)(ws + WS_TOKP);
        float* tw = (float*)(ws + WS_TOKW);
        te[2 * t] = e0; te[2 * t + 1] = e1;
        tp[2 * t] = p0; tp[2 * t + 1] = p1;
        tw[2 * t] = w0; tw[2 * t + 1] = w1;
    }
}

// ---------------- 2. scan (8 values) ----------------
__global__ void k_scan(char* __restrict__ ws) {
    if (threadIdx.x == 0) {
        int* c = (int*)(ws + WS_CNT);
        int* b = (int*)(ws + WS_BASE);
        int s = 0;
        for (int e = 0; e < NEXP; ++e) { b[e] = s; s += c[e]; }
    }
}

// ---------------- 3. gather x rows -> fp16, expert-contiguous ----------------
__global__ __launch_bounds__(256) void k_gather(const float* __restrict__ x,
                                                char* __restrict__ ws) {
    int pair = blockIdx.x;            // 4096 = token*2 + k
    int t = pair >> 1, k = pair & 1;
    int e = ((int*)(ws + WS_TOKE))[2 * t + k];
    int p = ((int*)(ws + WS_TOKP))[2 * t + k];
    int slot = ((int*)(ws + WS_BASE))[e] + p;

    const float4* src = (const float4*)(x + (size_t)t * DMODEL);
    u16* xg = (u16*)(ws + WS_XG);
    float4 v = src[threadIdx.x];
    uint2 o;
    o.x = (uint)f2h(v.x) | ((uint)f2h(v.y) << 16);
    o.y = (uint)f2h(v.z) | ((uint)f2h(v.w) << 16);
    ((uint2*)(xg + (size_t)slot * DMODEL))[threadIdx.x] = o;
}

// ---------------- GEMM tiling ----------------
#define BM 128
#define BN 64
#define BK 32
#define LSTR 40   // LDS row stride in f16 elems (80 B) -> <=2-way bank alias

// 4. fused gate/up GEMM + SwiGLU:  h = silu(xg @ W1^T) * (xg @ W3^T)
__global__ __launch_bounds__(256) void k_gemm1(const float* __restrict__ w1,
                                               const float* __restrict__ w3,
                                               char* __restrict__ ws) {
    int e  = blockIdx.z;
    int cn = ((const int*)(ws + WS_CNT))[e];
    int m0 = blockIdx.y * BM;
    if (m0 >= cn) return;
    int bas = ((const int*)(ws + WS_BASE))[e];
    int n0  = blockIdx.x * BN;

    __shared__ __align__(16) u16 sA[BM * LSTR];
    __shared__ __align__(16) u16 sB1[BN * LSTR];
    __shared__ __align__(16) u16 sB3[BN * LSTR];

    const u16* xg = (const u16*)(ws + WS_XG);
    u16* hbuf = (u16*)(ws + WS_H);
    const float* W1 = w1 + (size_t)e * DFF * DMODEL;
    const float* W3 = w3 + (size_t)e * DFF * DMODEL;

    int tid = threadIdx.x;
    int seg = tid & 3;        // k-chunk of 8
    int rqa = tid >> 2;       // 0..63
    int wid = tid >> 6, lane = tid & 63;
    int wr = wid >> 1, wc = wid & 1;
    int lrow = lane & 15, lk = (lane >> 4) * 8;

    f32x4 acc1[4][2] = {};
    f32x4 acc3[4][2] = {};

    for (int ks = 0; ks < DMODEL / BK; ++ks) {
        int k0 = ks * BK;
        // stage A (fp16 already): 2 rows x 8 elems per thread
        {
            uint4 v0 = *(const uint4*)(xg + (size_t)(bas + m0 + rqa) * DMODEL + k0 + seg * 8);
            uint4 v1 = *(const uint4*)(xg + (size_t)(bas + m0 + rqa + 64) * DMODEL + k0 + seg * 8);
            *(uint4*)&sA[rqa * LSTR + seg * 8] = v0;
            *(uint4*)&sA[(rqa + 64) * LSTR + seg * 8] = v1;
        }
        // stage B1/B3 (fp32 -> fp16)
        {
            const float4* p1 = (const float4*)(W1 + (size_t)(n0 + rqa) * DMODEL + k0 + seg * 8);
            *(uint4*)&sB1[rqa * LSTR + seg * 8] = pack8h(p1[0], p1[1]);
            const float4* p3 = (const float4*)(W3 + (size_t)(n0 + rqa) * DMODEL + k0 + seg * 8);
            *(uint4*)&sB3[rqa * LSTR + seg * 8] = pack8h(p3[0], p3[1]);
        }
        __syncthreads();

        half8 af[4], b1f[2], b3f[2];
#pragma unroll
        for (int m = 0; m < 4; ++m)
            af[m] = *(const half8*)&sA[(wr * 64 + m * 16 + lrow) * LSTR + lk];
#pragma unroll
        for (int n = 0; n < 2; ++n) {
            b1f[n] = *(const half8*)&sB1[(wc * 32 + n * 16 + lrow) * LSTR + lk];
            b3f[n] = *(const half8*)&sB3[(wc * 32 + n * 16 + lrow) * LSTR + lk];
        }
#pragma unroll
        for (int m = 0; m < 4; ++m)
#pragma unroll
            for (int n = 0; n < 2; ++n) {
                acc1[m][n] = __builtin_amdgcn_mfma_f32_16x16x32_f16(af[m], b1f[n], acc1[m][n], 0, 0, 0);
                acc3[m][n] = __builtin_amdgcn_mfma_f32_16x16x32_f16(af[m], b3f[n], acc3[m][n], 0, 0, 0);
            }
        __syncthreads();
    }

    // epilogue: silu(s1)*s3 -> fp16 h
#pragma unroll
    for (int m = 0; m < 4; ++m) {
        int rb = wr * 64 + m * 16 + (lane >> 4) * 4;
#pragma unroll
        for (int j = 0; j < 4; ++j) {
            int grow = m0 + rb + j;
            if (grow < cn) {
                size_t rowoff = (size_t)(bas + grow) * DFF;
#pragma unroll
                for (int n = 0; n < 2; ++n) {
                    float s1 = acc1[m][n][j];
                    float s3 = acc3[m][n][j];
                    float hv = (s1 / (1.f + expf(-s1))) * s3;
                    int gcol = n0 + wc * 32 + n * 16 + lrow;
                    hbuf[rowoff + gcol] = f2h(hv);
                }
            }
        }
    }
}

// 5. down GEMM: y = h @ W2^T   (fp32 out)
__global__ __launch_bounds__(256) void k_gemm2(const float* __restrict__ w2,
                                               char* __restrict__ ws) {
    int e  = blockIdx.z;
    int cn = ((const int*)(ws + WS_CNT))[e];
    int m0 = blockIdx.y * BM;
    if (m0 >= cn) return;
    int bas = ((const int*)(ws + WS_BASE))[e];
    int n0  = blockIdx.x * BN;

    __shared__ __align__(16) u16 sA[BM * LSTR];
    __shared__ __align__(16) u16 sB[BN * LSTR];

    const u16* hbuf = (const u16*)(ws + WS_H);
    const float* W2 = w2 + (size_t)e * DMODEL * DFF;
    float* y = (float*)(ws + WS_Y);

    int tid = threadIdx.x;
    int seg = tid & 3;
    int rqa = tid >> 2;
    int wid = tid >> 6, lane = tid & 63;
    int wr = wid >> 1, wc = wid & 1;
    int lrow = lane & 15, lk = (lane >> 4) * 8;

    f32x4 acc[4][2] = {};

    for (int ks = 0; ks < DFF / BK; ++ks) {
        int k0 = ks * BK;
        {
            uint4 v0 = *(const uint4*)(hbuf + (size_t)(bas + m0 + rqa) * DFF + k0 + seg * 8);
            uint4 v1 = *(const uint4*)(hbuf + (size_t)(bas + m0 + rqa + 64) * DFF + k0 + seg * 8);
            *(uint4*)&sA[rqa * LSTR + seg * 8] = v0;
            *(uint4*)&sA[(rqa + 64) * LSTR + seg * 8] = v1;
        }
        {
            const float4* p = (const float4*)(W2 + (size_t)(n0 + rqa) * DFF + k0 + seg * 8);
            *(uint4*)&sB[rqa * LSTR + seg * 8] = pack8h(p[0], p[1]);
        }
        __syncthreads();

        half8 af[4], bf[2];
#pragma unroll
        for (int m = 0; m < 4; ++m)
            af[m] = *(const half8*)&sA[(wr * 64 + m * 16 + lrow) * LSTR + lk];
#pragma unroll
        for (int n = 0; n < 2; ++n)
            bf[n] = *(const half8*)&sB[(wc * 32 + n * 16 + lrow) * LSTR + lk];
#pragma unroll
        for (int m = 0; m < 4; ++m)
#pragma unroll
            for (int n = 0; n < 2; ++n)
                acc[m][n] = __builtin_amdgcn_mfma_f32_16x16x32_f16(af[m], bf[n], acc[m][n], 0, 0, 0);
        __syncthreads();
    }

#pragma unroll
    for (int m = 0; m < 4; ++m) {
        int rb = wr * 64 + m * 16 + (lane >> 4) * 4;
#pragma unroll
        for (int j = 0; j < 4; ++j) {
            int grow = m0 + rb + j;
            if (grow < cn) {
#pragma unroll
                for (int n = 0; n < 2; ++n) {
                    int gcol = n0 + wc * 32 + n * 16 + lrow;
                    y[(size_t)(bas + grow) * DMODEL + gcol] = acc[m][n][j];
                }
            }
        }
    }
}

// 6. combine: out[t] = w0*y[s0] + w1*y[s1]
__global__ __launch_bounds__(256) void k_combine(const char* __restrict__ ws,
                                                 float* __restrict__ out) {
    int t = blockIdx.x;
    const int*   te = (const int*)(ws + WS_TOKE);
    const int*   tp = (const int*)(ws + WS_TOKP);
    const float* tw = (const float*)(ws + WS_TOKW);
    const int*   bs = (const int*)(ws + WS_BASE);
    const float* y  = (const float*)(ws + WS_Y);

    int s0 = bs[te[2 * t]] + tp[2 * t];
    int s1 = bs[te[2 * t + 1]] + tp[2 * t + 1];
    float w0 = tw[2 * t], w1 = tw[2 * t + 1];

    const float4* y0 = (const float4*)(y + (size_t)s0 * DMODEL);
    const float4* y1 = (const float4*)(y + (size_t)s1 * DMODEL);
    float4 a = y0[threadIdx.x];
    float4 b = y1[threadIdx.x];
    float4 r;
    r.x = w0 * a.x + w1 * b.x;
    r.y = w0 * a.y + w1 * b.y;
    r.z = w0 * a.z + w1 * b.z;
    r.w = w0 * a.w + w1 * b.w;
    ((float4*)(out + (size_t)t * DMODEL))[threadIdx.x] = r;
}

extern "C" void kernel_launch(void* const* d_in, const int* in_sizes, int n_in,
                              void* d_out, int out_size, void* d_ws, size_t ws_size,
                              hipStream_t stream) {
    const float* x  = (const float*)d_in[0];
    const float* wr = (const float*)d_in[1];
    const float* w1 = (const float*)d_in[2];
    const float* w2 = (const float*)d_in[3];
    const float* w3 = (const float*)d_in[4];
    char* ws = (char*)d_ws;

    hipMemsetAsync(d_ws, 0, 256, stream);                       // zero counters
    k_router <<<T_TOK / 4, 256, 0, stream>>>(x, wr, ws);
    k_scan   <<<1, 64, 0, stream>>>(ws);
    k_gather <<<2 * T_TOK, 256, 0, stream>>>(x, ws);
    k_gemm1  <<<dim3(DFF / BN, T_TOK / BM, NEXP), 256, 0, stream>>>(w1, w3, ws);
    k_gemm2  <<<dim3(DMODEL / BN, T_TOK / BM, NEXP), 256, 0, stream>>>(w2, ws);
    k_combine<<<T_TOK, 256, 0, stream>>>(ws, (float*)d_out);
}